// Round 17
// baseline (194.683 us; speedup 1.0000x reference)
//
#include <hip/hip_runtime.h>
#include <hip/hip_bf16.h>
#include <math.h>

#define D 256
#define S 4096
#define BATCH 4
#define RPB 32                    // rows per fused block (2 Mt tiles)
#define NBLK (BATCH * S / RPB)    // 512 fused blocks
#define DT_CUT 7.0f
#define REP 16                    // DIAGNOSTIC: idempotent repeat (fused only)

typedef __attribute__((ext_vector_type(8))) short short8;
typedef __attribute__((ext_vector_type(4))) float f32x4;

static __device__ __forceinline__ unsigned short f2bf(float x) {
    union { __hip_bfloat16 b; unsigned short u; } cv;
    cv.b = __float2bfloat16(x);    // HW RNE convert; compiler packs pairs
    return cv.u;
}

// ===========================================================================
// w5 fragment-tiled layout:  w5: tile (et16*8 + kt), elem = lane*8 + ee
//                  (e = et16*16 + (lane&15), d = kt*32 + (lane>>4)*8 + ee)
// Embedding computed on the fly (R13: materialized emb = 64 MB/rep L2-miss).
// Scalar f2bf only (R15: hand-written cvt_pk asm broke correctness).
// ===========================================================================

// ---------------------------------------------------------------------------
// K1 (tiny): W -> w5 fragment tiles; band-start jcmin for 2 fused blocks.
// ---------------------------------------------------------------------------
__global__ __launch_bounds__(256) void prep_kernel(const float* __restrict__ t,
                                                   const float* __restrict__ W,
                                                   unsigned short* __restrict__ w5,
                                                   int* __restrict__ jcmin_out) {
    int blk = blockIdx.x;      // 256 blocks
    int tid = threadIdx.x;

    {   // W[e][d] -> w5 fragment tiles (row e = blk)
        int e = blk, dd = tid;
        int et16 = e >> 4, l15 = e & 15;
        int kt = dd >> 5, kgg = (dd >> 3) & 3, ee = dd & 7;
        w5[(size_t)((et16 * 8 + kt) * 512) + (kgg * 16 + l15) * 8 + ee]
            = f2bf(W[e * D + dd]);
    }

    // wave 0: band-start searches for fused blocks 2*blk, 2*blk+1
    if (tid < 64) {
#pragma unroll
        for (int s = 0; s < 2; ++s) {
            int fb = blk * 2 + s;
            int b2 = fb >> 7;
            int i0 = (fb & 127) * RPB;
            const float* tb2 = t + b2 * S;
            float tcut = tb2[i0] - DT_CUT;
            int lo = 0, hi = i0;                 // invariant: t[hi] >= tcut
            while (hi > lo) {
                int step = ((hi - lo) + 63) >> 6;
                int p = min(lo + tid * step, hi);
                unsigned long long mb = __ballot(tb2[p] < tcut);
                int cnt = __popcll(mb);
                int nlo = (cnt == 0) ? lo : (lo + (cnt - 1) * step + 1);
                int nhi = (cnt == 0) ? nlo : min(lo + cnt * step, hi);
                lo = nlo; hi = nhi;
            }
            if (tid == 0) jcmin_out[fb] = lo >> 5;
        }
    }
}

// ---------------------------------------------------------------------------
// K2: fused band-GEMM (on-the-fly B) + LayerNorm + decoder-GEMM + softplus.
// EXACT R16 structure, wrapped in idempotent REP loop for counter visibility.
// ---------------------------------------------------------------------------
__global__ __launch_bounds__(256, 2) void fused_kernel(
    const float* __restrict__ t, const unsigned short* __restrict__ w5,
    const int* __restrict__ jcmin_arr,
    const float* __restrict__ gamma, const float* __restrict__ beta,
    const float* __restrict__ w_t, const float* __restrict__ b_t,
    float* __restrict__ out) {
    int bid  = blockIdx.x;
    int blk  = (bid & 7) * (NBLK / 8) + (bid >> 3);   // XCD swizzle (bijective)
    int b    = blk >> 7;                 // 128 blocks per batch
    int i0   = (blk & 127) * RPB;
    int tid  = threadIdx.x;
    int w    = tid >> 6;
    int lane = tid & 63;
    int ln15 = lane & 15;
    int kg   = lane >> 4;
    const float* tb = t + b * S;

    float ti0 = tb[i0 + ln15], ti1 = tb[i0 + 16 + ln15];
    int   ir0 = i0 + ln15,     ir1 = i0 + 16 + ln15;
    int jcmin = jcmin_arr[blk];
    int jcmax = i0 >> 5;                 // diagonal chunk (serves both Mt)

    const float c2 = -0.1038102552f;     // -2*log2(10000)/256
    float cr[4];
#pragma unroll
    for (int nt = 0; nt < 4; ++nt) {
        int d = w * 64 + nt * 16 + ln15;
        cr[nt] = exp2f(c2 * (float)((d >> 1) + 1));
    }
    float phase = (ln15 & 1) ? 1.5707963268f : 0.0f;  // cos = sin(x + pi/2)

    __shared__ float2 s_ln[4][RPB];
    __shared__ unsigned short H[RPB][264];       // +8 pad
    __shared__ float s_dec[4][RPB];

    float g[4], be[4], wt[4];
#pragma unroll
    for (int nt = 0; nt < 4; ++nt) {
        g[nt]  = gamma[w * 64 + nt * 16 + ln15];
        be[nt] = beta[w * 64 + nt * 16 + ln15];
        wt[nt] = w_t[w * 64 + nt * 16 + ln15];
    }
    const unsigned short* wbase = w5 + (size_t)(w * 4 * 8) * 512 + lane * 8;

    for (int rep = 0; rep < REP; ++rep) {
    __syncthreads();                     // protect LDS reuse across reps

    // ---- band GEMM: C[m, d] += scores[m, k] * emb[k, d]  (B on the fly)
    f32x4 acc[2][4];
#pragma unroll
    for (int Mt = 0; Mt < 2; ++Mt)
#pragma unroll
        for (int nt = 0; nt < 4; ++nt) acc[Mt][nt] = (f32x4){0.f, 0.f, 0.f, 0.f};

    for (int jc = jcmin; jc < jcmax; ++jc) {      // fully-causal chunks
        int j0 = jc * 32;
        float4 ta4 = *(const float4*)&tb[j0 + kg * 8];
        float4 tb4 = *(const float4*)&tb[j0 + kg * 8 + 4];
        float tj[8] = {ta4.x, ta4.y, ta4.z, ta4.w, tb4.x, tb4.y, tb4.z, tb4.w};

        union { short8 v; unsigned short u[8]; } a0, a1;
#pragma unroll
        for (int e = 0; e < 8; ++e) {
            float d0 = ti0 - tj[e], d1 = ti1 - tj[e];
            a0.u[e] = f2bf(__expf(-0.5f * d0 * d0));
            a1.u[e] = f2bf(__expf(-0.5f * d1 * d1));
        }
#pragma unroll
        for (int nt = 0; nt < 4; ++nt) {
            union { short8 v; unsigned short u[8]; } bf;
#pragma unroll
            for (int e = 0; e < 8; ++e)
                bf.u[e] = f2bf(__sinf(fmaf(tj[e], cr[nt], phase)));
            acc[0][nt] = __builtin_amdgcn_mfma_f32_16x16x32_bf16(a0.v, bf.v, acc[0][nt], 0, 0, 0);
            acc[1][nt] = __builtin_amdgcn_mfma_f32_16x16x32_bf16(a1.v, bf.v, acc[1][nt], 0, 0, 0);
        }
    }
    {   // peeled diagonal chunk jc == jcmax (causal masks for both Mt)
        int j0 = jcmax * 32;
        float4 ta4 = *(const float4*)&tb[j0 + kg * 8];
        float4 tb4 = *(const float4*)&tb[j0 + kg * 8 + 4];
        float tj[8] = {ta4.x, ta4.y, ta4.z, ta4.w, tb4.x, tb4.y, tb4.z, tb4.w};

        union { short8 v; unsigned short u[8]; } a0, a1;
#pragma unroll
        for (int e = 0; e < 8; ++e) {
            int j = j0 + kg * 8 + e;
            float d0 = ti0 - tj[e], d1 = ti1 - tj[e];
            float s0 = __expf(-0.5f * d0 * d0), s1 = __expf(-0.5f * d1 * d1);
            a0.u[e] = (j <= ir0) ? f2bf(s0) : (unsigned short)0;
            a1.u[e] = (j <= ir1) ? f2bf(s1) : (unsigned short)0;
        }
#pragma unroll
        for (int nt = 0; nt < 4; ++nt) {
            union { short8 v; unsigned short u[8]; } bf;
#pragma unroll
            for (int e = 0; e < 8; ++e)
                bf.u[e] = f2bf(__sinf(fmaf(tj[e], cr[nt], phase)));
            acc[0][nt] = __builtin_amdgcn_mfma_f32_16x16x32_bf16(a0.v, bf.v, acc[0][nt], 0, 0, 0);
            acc[1][nt] = __builtin_amdgcn_mfma_f32_16x16x32_bf16(a1.v, bf.v, acc[1][nt], 0, 0, 0);
        }
    }

    // ---- hoist decoder kt=0 weight frags (independent of LN barriers)
    short8 w0 = *(const short8*)(wbase + (size_t)(0 * 8) * 512);
    short8 w1 = *(const short8*)(wbase + (size_t)(1 * 8) * 512);
    short8 w2 = *(const short8*)(wbase + (size_t)(2 * 8) * 512);
    short8 w3 = *(const short8*)(wbase + (size_t)(3 * 8) * 512);

    // ---- LayerNorm (row r = Mt*16 + kg*4 + reg; col d = w*64 + nt*16 + ln15)
#pragma unroll
    for (int Mt = 0; Mt < 2; ++Mt)
#pragma unroll
        for (int reg = 0; reg < 4; ++reg) {
            float s = acc[Mt][0][reg] + acc[Mt][1][reg] + acc[Mt][2][reg] + acc[Mt][3][reg];
            float q = acc[Mt][0][reg] * acc[Mt][0][reg] + acc[Mt][1][reg] * acc[Mt][1][reg]
                    + acc[Mt][2][reg] * acc[Mt][2][reg] + acc[Mt][3][reg] * acc[Mt][3][reg];
#pragma unroll
            for (int m = 1; m < 16; m <<= 1) {
                s += __shfl_xor(s, m);
                q += __shfl_xor(q, m);
            }
            if (ln15 == 0) s_ln[w][Mt * 16 + kg * 4 + reg] = make_float2(s, q);
        }
    __syncthreads();

#pragma unroll
    for (int Mt = 0; Mt < 2; ++Mt)
#pragma unroll
        for (int reg = 0; reg < 4; ++reg) {
            int r = Mt * 16 + kg * 4 + reg;
            float2 p0 = s_ln[0][r], p1 = s_ln[1][r], p2 = s_ln[2][r], p3 = s_ln[3][r];
            float sum = p0.x + p1.x + p2.x + p3.x;
            float sq  = p0.y + p1.y + p2.y + p3.y;
            float mu  = sum * (1.0f / D);
            float var = fmaxf(sq * (1.0f / D) - mu * mu, 0.0f);
            float rstd = rsqrtf(var + 1e-6f);
#pragma unroll
            for (int nt = 0; nt < 4; ++nt) {
                float h = (acc[Mt][nt][reg] - mu) * rstd * g[nt] + be[nt];
                H[r][w * 64 + nt * 16 + ln15] = f2bf(h);
            }
        }
    __syncthreads();

    // ---- decoder GEMM: C2[m, e] = sum_d H[m, d] * W[e, d], kt pipelined;
    //      W-frags reused across both Mt tiles.
    f32x4 acc2[2][4];
#pragma unroll
    for (int Mt = 0; Mt < 2; ++Mt)
#pragma unroll
        for (int et = 0; et < 4; ++et) acc2[Mt][et] = (f32x4){0.f, 0.f, 0.f, 0.f};

#pragma unroll
    for (int kt = 0; kt < 8; ++kt) {
        short8 nw0, nw1, nw2, nw3;
        if (kt < 7) {
            const unsigned short* p = wbase + (size_t)(kt + 1) * 512;
            nw0 = *(const short8*)(p + (size_t)(0 * 8) * 512);
            nw1 = *(const short8*)(p + (size_t)(1 * 8) * 512);
            nw2 = *(const short8*)(p + (size_t)(2 * 8) * 512);
            nw3 = *(const short8*)(p + (size_t)(3 * 8) * 512);
        }
        short8 a0 = *(const short8*)&H[ln15][kt * 32 + kg * 8];
        short8 a1 = *(const short8*)&H[16 + ln15][kt * 32 + kg * 8];
        acc2[0][0] = __builtin_amdgcn_mfma_f32_16x16x32_bf16(a0, w0, acc2[0][0], 0, 0, 0);
        acc2[0][1] = __builtin_amdgcn_mfma_f32_16x16x32_bf16(a0, w1, acc2[0][1], 0, 0, 0);
        acc2[0][2] = __builtin_amdgcn_mfma_f32_16x16x32_bf16(a0, w2, acc2[0][2], 0, 0, 0);
        acc2[0][3] = __builtin_amdgcn_mfma_f32_16x16x32_bf16(a0, w3, acc2[0][3], 0, 0, 0);
        acc2[1][0] = __builtin_amdgcn_mfma_f32_16x16x32_bf16(a1, w0, acc2[1][0], 0, 0, 0);
        acc2[1][1] = __builtin_amdgcn_mfma_f32_16x16x32_bf16(a1, w1, acc2[1][1], 0, 0, 0);
        acc2[1][2] = __builtin_amdgcn_mfma_f32_16x16x32_bf16(a1, w2, acc2[1][2], 0, 0, 0);
        acc2[1][3] = __builtin_amdgcn_mfma_f32_16x16x32_bf16(a1, w3, acc2[1][3], 0, 0, 0);
        w0 = nw0; w1 = nw1; w2 = nw2; w3 = nw3;
    }

    // ---- epilogue: relu -> *w_t -> reduce over e -> softplus
#pragma unroll
    for (int Mt = 0; Mt < 2; ++Mt)
#pragma unroll
        for (int reg = 0; reg < 4; ++reg) {
            float v = 0.f;
#pragma unroll
            for (int et = 0; et < 4; ++et)
                v = fmaf(fmaxf(acc2[Mt][et][reg], 0.f), wt[et], v);
#pragma unroll
            for (int m = 1; m < 16; m <<= 1) v += __shfl_xor(v, m);
            if (ln15 == 0) s_dec[w][Mt * 16 + kg * 4 + reg] = v;
        }
    __syncthreads();
    if (tid < RPB) {
        float tot = s_dec[0][tid] + s_dec[1][tid] + s_dec[2][tid] + s_dec[3][tid] + b_t[0];
        float o = fmaxf(tot, 0.0f) + log1pf(expf(-fabsf(tot)));   // softplus
        out[(size_t)blk * RPB + tid] = o;
    }
    }   // rep
}

// ---------------------------------------------------------------------------
extern "C" void kernel_launch(void* const* d_in, const int* in_sizes, int n_in,
                              void* d_out, int out_size, void* d_ws, size_t ws_size,
                              hipStream_t stream) {
    // inputs: 0 event_type(i32) 1 event_time(f32) 2 arrival_times(f32)
    //         3 W_in 4 w_t 5 b_t 6 ln_gamma 7 ln_beta
    const float* t   = (const float*)d_in[1];
    const float* W   = (const float*)d_in[3];
    const float* wt  = (const float*)d_in[4];
    const float* bt  = (const float*)d_in[5];
    const float* gam = (const float*)d_in[6];
    const float* bet = (const float*)d_in[7];
    float* out = (float*)d_out;

    char* ws = (char*)d_ws;
    unsigned short* w5    = (unsigned short*)ws;                 // 128 KiB
    int*            jcmin = (int*)(ws + (size_t)131072);         // 2 KiB

    prep_kernel<<<dim3(256), dim3(256), 0, stream>>>(t, W, w5, jcmin);
    fused_kernel<<<dim3(NBLK), dim3(256), 0, stream>>>(
        t, w5, jcmin, gam, bet, wt, bt, out);
}

// Round 18
// 25.431 us; speedup vs baseline: 7.6554x; 7.6554x over previous
//
#include <hip/hip_runtime.h>
#include <hip/hip_bf16.h>
#include <math.h>

#define D 256
#define S 4096
#define BATCH 4
#define RPB 64                    // rows per fused block (4 Mt tiles)
#define NBLK (BATCH * S / RPB)    // 256 fused blocks
#define DT_CUT 7.0f

typedef __attribute__((ext_vector_type(8))) short short8;
typedef __attribute__((ext_vector_type(4))) float f32x4;

static __device__ __forceinline__ unsigned short f2bf(float x) {
    union { __hip_bfloat16 b; unsigned short u; } cv;
    cv.b = __float2bfloat16(x);    // HW RNE convert; compiler packs pairs
    return cv.u;
}

// ===========================================================================
// R17 counters: VALUBusy 52%, MfmaUtil 12% -> issue-bound on fragment gen
// (A-scores 4x wave-redundant, B-sins regenerated per overlapping block).
// Fix: per chunk, 512 threads generate A (2048 exps) + B (8192 sins) ONCE
// into LDS fragment-tiled buffers (double-buffered, 1 barrier/chunk); 8
// waves then ds_read_b128 frags + 8 MFMA each. Trans work drops 2.4x.
// w5: tile (et16*8 + kt), elem = lane*8 + ee
//     (e = et16*16 + (lane&15), d = kt*32 + (lane>>4)*8 + ee)
// ===========================================================================

// ---------------------------------------------------------------------------
// K1 (tiny): W -> w5 fragment tiles; band-start jcmin per fused block.
// ---------------------------------------------------------------------------
__global__ __launch_bounds__(256) void prep_kernel(const float* __restrict__ t,
                                                   const float* __restrict__ W,
                                                   unsigned short* __restrict__ w5,
                                                   int* __restrict__ jcmin_out) {
    int blk = blockIdx.x;      // 256 blocks
    int tid = threadIdx.x;

    {   // W[e][d] -> w5 fragment tiles (row e = blk)
        int e = blk, dd = tid;
        int et16 = e >> 4, l15 = e & 15;
        int kt = dd >> 5, kgg = (dd >> 3) & 3, ee = dd & 7;
        w5[(size_t)((et16 * 8 + kt) * 512) + (kgg * 16 + l15) * 8 + ee]
            = f2bf(W[e * D + dd]);
    }

    // wave 0: band-start search for fused block == blk (RPB=64)
    if (tid < 64) {
        int b2 = blk >> 6;
        int i0 = (blk & 63) * RPB;
        const float* tb2 = t + b2 * S;
        float tcut = tb2[i0] - DT_CUT;
        int lo = 0, hi = i0;                 // invariant: t[hi] >= tcut
        while (hi > lo) {
            int step = ((hi - lo) + 63) >> 6;
            int p = min(lo + tid * step, hi);
            unsigned long long mb = __ballot(tb2[p] < tcut);
            int cnt = __popcll(mb);
            int nlo = (cnt == 0) ? lo : (lo + (cnt - 1) * step + 1);
            int nhi = (cnt == 0) ? nlo : min(lo + cnt * step, hi);
            lo = nlo; hi = nhi;
        }
        if (tid == 0) jcmin_out[blk] = lo >> 5;
    }
}

// ---------------------------------------------------------------------------
// K2: fused band-GEMM (LDS-shared frag gen) + LayerNorm + decoder + softplus.
// 512 threads = 8 waves; wave w owns cols [w*32, w*32+32) (2 nt tiles) x all
// 4 Mt row-tiles. Gen double-buffered; causal mask folded into A gen.
// ---------------------------------------------------------------------------
__global__ __launch_bounds__(512) void fused_kernel(
    const float* __restrict__ t, const unsigned short* __restrict__ w5,
    const int* __restrict__ jcmin_arr,
    const float* __restrict__ gamma, const float* __restrict__ beta,
    const float* __restrict__ w_t, const float* __restrict__ b_t,
    float* __restrict__ out) {
    int bid  = blockIdx.x;
    int blk  = (bid & 7) * (NBLK / 8) + (bid >> 3);   // XCD swizzle (bijective)
    int b    = blk >> 6;                 // 64 blocks per batch
    int i0   = (blk & 63) * RPB;
    int tid  = threadIdx.x;
    int w    = tid >> 6;                 // 0..7
    int lane = tid & 63;
    int ln15 = lane & 15;
    int kg   = lane >> 4;
    const float* tb = t + b * S;

    int jcmin = jcmin_arr[blk];
    int jcmax = (i0 + RPB - 1) >> 5;

    __shared__ unsigned short Ag[2][2048];   // [buf][mt*512 + l*8 + e]
    __shared__ unsigned short Bg[2][8192];   // [buf][nt*512 + l*8 + e]
    __shared__ unsigned short H[RPB][264];   // +8 pad
    __shared__ float2 s_ln[8][RPB];
    __shared__ float  s_mu[RPB], s_rs[RPB];
    __shared__ float  s_dec[8][RPB];

    // ---- hoisted per-thread gen constants
    // A: thread -> (mt, l, half): 4 exps/chunk
    int mtA  = tid >> 7;
    int lA   = (tid >> 1) & 63;
    int hA   = (tid & 1) * 4;
    int rowA = i0 + mtA * 16 + (lA & 15);
    float tiA = tb[rowA];
    int joffA = ((lA >> 4) << 3) + hA;
    int aidx  = mtA * 512 + lA * 8 + hA;
    // B: thread -> (nt, row-pair l/l+1): 8 sincos/chunk
    const float c2 = -0.1038102552f;     // -2*log2(10000)/256
    int ntB  = tid >> 5;
    int lB   = (tid * 2) & 63;           // even
    int dB   = ntB * 16 + (lB & 15);     // even d; d+1 shares k
    float crB = exp2f(c2 * (float)((dB >> 1) + 1));
    int joffB = (lB >> 4) << 3;
    int bidx0 = ntB * 512 + lB * 8;

    auto gen = [&](int buf, int j0) {
        // A scores (causal mask folded in; handles diagonal chunks too)
        float4 t4 = *(const float4*)&tb[j0 + joffA];
        unsigned short a4[4];
#pragma unroll
        for (int c = 0; c < 4; ++c) {
            float dd = tiA - ((const float*)&t4)[c];
            float s = __expf(-0.5f * dd * dd);
            a4[c] = (j0 + joffA + c <= rowA) ? f2bf(s) : (unsigned short)0;
        }
        unsigned long long apk = (unsigned long long)a4[0] |
            ((unsigned long long)a4[1] << 16) | ((unsigned long long)a4[2] << 32) |
            ((unsigned long long)a4[3] << 48);
        *(unsigned long long*)&Ag[buf][aidx] = apk;
        // B embedding: rows d (sin) and d+1 (cos), same angle
        float4 u4 = *(const float4*)&tb[j0 + joffB];
        float4 v4 = *(const float4*)&tb[j0 + joffB + 4];
        float tjv[8] = {u4.x, u4.y, u4.z, u4.w, v4.x, v4.y, v4.z, v4.w};
        union { short8 v; unsigned short u[8]; } b0, b1;
#pragma unroll
        for (int e = 0; e < 8; ++e) {
            float sn, cs;
            __sincosf(tjv[e] * crB, &sn, &cs);
            b0.u[e] = f2bf(sn);
            b1.u[e] = f2bf(cs);
        }
        *(short8*)&Bg[buf][bidx0]     = b0.v;
        *(short8*)&Bg[buf][bidx0 + 8] = b1.v;
    };

    // ---- band GEMM over chunks, double-buffered gen, 1 barrier/chunk
    f32x4 acc[4][2];
#pragma unroll
    for (int mt = 0; mt < 4; ++mt)
#pragma unroll
        for (int sub = 0; sub < 2; ++sub) acc[mt][sub] = (f32x4){0.f, 0.f, 0.f, 0.f};

    gen(0, jcmin * 32);
    for (int jc = jcmin; jc <= jcmax; ++jc) {
        __syncthreads();
        int buf = (jc - jcmin) & 1;
        if (jc < jcmax) gen(buf ^ 1, (jc + 1) * 32);
        short8 afr[4];
#pragma unroll
        for (int mt = 0; mt < 4; ++mt)
            afr[mt] = *(const short8*)&Ag[buf][mt * 512 + lane * 8];
        short8 bf0 = *(const short8*)&Bg[buf][(w * 2) * 512 + lane * 8];
        short8 bf1 = *(const short8*)&Bg[buf][(w * 2 + 1) * 512 + lane * 8];
#pragma unroll
        for (int mt = 0; mt < 4; ++mt) {
            acc[mt][0] = __builtin_amdgcn_mfma_f32_16x16x32_bf16(afr[mt], bf0, acc[mt][0], 0, 0, 0);
            acc[mt][1] = __builtin_amdgcn_mfma_f32_16x16x32_bf16(afr[mt], bf1, acc[mt][1], 0, 0, 0);
        }
    }

    // ---- LayerNorm: cross-wave (col-split) reduction
#pragma unroll
    for (int mt = 0; mt < 4; ++mt)
#pragma unroll
        for (int reg = 0; reg < 4; ++reg) {
            float v0 = acc[mt][0][reg], v1 = acc[mt][1][reg];
            float s = v0 + v1;
            float q = v0 * v0 + v1 * v1;
#pragma unroll
            for (int m = 1; m < 16; m <<= 1) {
                s += __shfl_xor(s, m);
                q += __shfl_xor(q, m);
            }
            if (ln15 == 0) s_ln[w][mt * 16 + kg * 4 + reg] = make_float2(s, q);
        }
    __syncthreads();
    if (tid < RPB) {
        float sum = 0.f, sq = 0.f;
#pragma unroll
        for (int ww = 0; ww < 8; ++ww) {
            float2 p = s_ln[ww][tid];
            sum += p.x; sq += p.y;
        }
        float mu  = sum * (1.0f / D);
        float var = fmaxf(sq * (1.0f / D) - mu * mu, 0.0f);
        s_mu[tid] = mu;
        s_rs[tid] = rsqrtf(var + 1e-6f);
    }
    __syncthreads();

    float g0 = gamma[w * 32 + ln15],      g1 = gamma[w * 32 + 16 + ln15];
    float be0 = beta[w * 32 + ln15],      be1 = beta[w * 32 + 16 + ln15];
#pragma unroll
    for (int mt = 0; mt < 4; ++mt)
#pragma unroll
        for (int reg = 0; reg < 4; ++reg) {
            int r = mt * 16 + kg * 4 + reg;
            float mu = s_mu[r], rstd = s_rs[r];
            H[r][w * 32 + ln15]      = f2bf((acc[mt][0][reg] - mu) * rstd * g0 + be0);
            H[r][w * 32 + 16 + ln15] = f2bf((acc[mt][1][reg] - mu) * rstd * g1 + be1);
        }
    __syncthreads();

    // ---- decoder GEMM: wave w -> e-cols [w*32, w*32+32), kt pipelined
    const unsigned short* wb0 = w5 + (size_t)((w * 2 + 0) * 8) * 512 + lane * 8;
    const unsigned short* wb1 = w5 + (size_t)((w * 2 + 1) * 8) * 512 + lane * 8;
    short8 W0 = *(const short8*)wb0;
    short8 W1 = *(const short8*)wb1;

    f32x4 acc2[4][2];
#pragma unroll
    for (int mt = 0; mt < 4; ++mt)
#pragma unroll
        for (int sub = 0; sub < 2; ++sub) acc2[mt][sub] = (f32x4){0.f, 0.f, 0.f, 0.f};

#pragma unroll
    for (int kt = 0; kt < 8; ++kt) {
        short8 nW0, nW1;
        if (kt < 7) {
            nW0 = *(const short8*)(wb0 + (size_t)(kt + 1) * 512);
            nW1 = *(const short8*)(wb1 + (size_t)(kt + 1) * 512);
        }
        short8 a[4];
#pragma unroll
        for (int mt = 0; mt < 4; ++mt)
            a[mt] = *(const short8*)&H[mt * 16 + ln15][kt * 32 + kg * 8];
#pragma unroll
        for (int mt = 0; mt < 4; ++mt) {
            acc2[mt][0] = __builtin_amdgcn_mfma_f32_16x16x32_bf16(a[mt], W0, acc2[mt][0], 0, 0, 0);
            acc2[mt][1] = __builtin_amdgcn_mfma_f32_16x16x32_bf16(a[mt], W1, acc2[mt][1], 0, 0, 0);
        }
        W0 = nW0; W1 = nW1;
    }

    // ---- epilogue: relu -> *w_t -> cross-wave reduce -> softplus
    float wt0 = w_t[w * 32 + ln15], wt1 = w_t[w * 32 + 16 + ln15];
#pragma unroll
    for (int mt = 0; mt < 4; ++mt)
#pragma unroll
        for (int reg = 0; reg < 4; ++reg) {
            float v = fmaf(fmaxf(acc2[mt][0][reg], 0.f), wt0,
                           fmaxf(acc2[mt][1][reg], 0.f) * wt1);
#pragma unroll
            for (int m = 1; m < 16; m <<= 1) v += __shfl_xor(v, m);
            if (ln15 == 0) s_dec[w][mt * 16 + kg * 4 + reg] = v;
        }
    __syncthreads();
    if (tid < RPB) {
        float tot = b_t[0];
#pragma unroll
        for (int ww = 0; ww < 8; ++ww) tot += s_dec[ww][tid];
        float o = fmaxf(tot, 0.0f) + log1pf(expf(-fabsf(tot)));   // softplus
        out[(size_t)blk * RPB + tid] = o;
    }
}

// ---------------------------------------------------------------------------
extern "C" void kernel_launch(void* const* d_in, const int* in_sizes, int n_in,
                              void* d_out, int out_size, void* d_ws, size_t ws_size,
                              hipStream_t stream) {
    // inputs: 0 event_type(i32) 1 event_time(f32) 2 arrival_times(f32)
    //         3 W_in 4 w_t 5 b_t 6 ln_gamma 7 ln_beta
    const float* t   = (const float*)d_in[1];
    const float* W   = (const float*)d_in[3];
    const float* wt  = (const float*)d_in[4];
    const float* bt  = (const float*)d_in[5];
    const float* gam = (const float*)d_in[6];
    const float* bet = (const float*)d_in[7];
    float* out = (float*)d_out;

    char* ws = (char*)d_ws;
    unsigned short* w5    = (unsigned short*)ws;                 // 128 KiB
    int*            jcmin = (int*)(ws + (size_t)131072);         // 1 KiB

    prep_kernel<<<dim3(256), dim3(256), 0, stream>>>(t, W, w5, jcmin);
    fused_kernel<<<dim3(NBLK), dim3(512), 0, stream>>>(
        t, w5, jcmin, gam, bet, wt, bt, out);
}

// Round 19
// 22.763 us; speedup vs baseline: 8.5525x; 1.1172x over previous
//
#include <hip/hip_runtime.h>
#include <hip/hip_bf16.h>
#include <math.h>

#define D 256
#define S 4096
#define BATCH 4
#define RPB 32                    // rows per fused block (2 Mt tiles)
#define NBLK (BATCH * S / RPB)    // 512 fused blocks
#define DT_CUT 4.5f               // R19: 7.0->4.5; omitted-score sum ~2e-4 pre-LN

typedef __attribute__((ext_vector_type(8))) short short8;
typedef __attribute__((ext_vector_type(4))) float f32x4;

static __device__ __forceinline__ unsigned short f2bf(float x) {
    union { __hip_bfloat16 b; unsigned short u; } cv;
    cv.b = __float2bfloat16(x);    // HW RNE convert; compiler packs pairs
    return cv.u;
}

// ===========================================================================
// w5 fragment-tiled layout:  w5: tile (et16*8 + kt), elem = lane*8 + ee
//                  (e = et16*16 + (lane&15), d = kt*32 + (lane>>4)*8 + ee)
// Embedding computed on the fly (R13: materialized emb = 64 MB/rep L2-miss).
// Scalar f2bf only (R15: hand-written cvt_pk asm broke correctness).
// R16 structure unchanged; only DT_CUT narrowed (validated by error budget).
// ===========================================================================

// ---------------------------------------------------------------------------
// K1 (tiny): W -> w5 fragment tiles; band-start jcmin for 2 fused blocks.
// ---------------------------------------------------------------------------
__global__ __launch_bounds__(256) void prep_kernel(const float* __restrict__ t,
                                                   const float* __restrict__ W,
                                                   unsigned short* __restrict__ w5,
                                                   int* __restrict__ jcmin_out) {
    int blk = blockIdx.x;      // 256 blocks
    int tid = threadIdx.x;

    {   // W[e][d] -> w5 fragment tiles (row e = blk)
        int e = blk, dd = tid;
        int et16 = e >> 4, l15 = e & 15;
        int kt = dd >> 5, kgg = (dd >> 3) & 3, ee = dd & 7;
        w5[(size_t)((et16 * 8 + kt) * 512) + (kgg * 16 + l15) * 8 + ee]
            = f2bf(W[e * D + dd]);
    }

    // wave 0: band-start searches for fused blocks 2*blk, 2*blk+1
    if (tid < 64) {
#pragma unroll
        for (int s = 0; s < 2; ++s) {
            int fb = blk * 2 + s;
            int b2 = fb >> 7;
            int i0 = (fb & 127) * RPB;
            const float* tb2 = t + b2 * S;
            float tcut = tb2[i0] - DT_CUT;
            int lo = 0, hi = i0;                 // invariant: t[hi] >= tcut
            while (hi > lo) {
                int step = ((hi - lo) + 63) >> 6;
                int p = min(lo + tid * step, hi);
                unsigned long long mb = __ballot(tb2[p] < tcut);
                int cnt = __popcll(mb);
                int nlo = (cnt == 0) ? lo : (lo + (cnt - 1) * step + 1);
                int nhi = (cnt == 0) ? nlo : min(lo + cnt * step, hi);
                lo = nlo; hi = nhi;
            }
            if (tid == 0) jcmin_out[fb] = lo >> 5;
        }
    }
}

// ---------------------------------------------------------------------------
// K2: fused band-GEMM (on-the-fly B) + LayerNorm + decoder-GEMM + softplus.
// Block = 32 rows (2 Mt) x 256 d/e, 4 waves; B-fragment sin generation
// shared across both Mt tiles. EXACT R16 structure.
// ---------------------------------------------------------------------------
__global__ __launch_bounds__(256, 2) void fused_kernel(
    const float* __restrict__ t, const unsigned short* __restrict__ w5,
    const int* __restrict__ jcmin_arr,
    const float* __restrict__ gamma, const float* __restrict__ beta,
    const float* __restrict__ w_t, const float* __restrict__ b_t,
    float* __restrict__ out) {
    int bid  = blockIdx.x;
    int blk  = (bid & 7) * (NBLK / 8) + (bid >> 3);   // XCD swizzle (bijective)
    int b    = blk >> 7;                 // 128 blocks per batch
    int i0   = (blk & 127) * RPB;
    int tid  = threadIdx.x;
    int w    = tid >> 6;
    int lane = tid & 63;
    int ln15 = lane & 15;
    int kg   = lane >> 4;
    const float* tb = t + b * S;

    float ti0 = tb[i0 + ln15], ti1 = tb[i0 + 16 + ln15];
    int   ir0 = i0 + ln15,     ir1 = i0 + 16 + ln15;
    int jcmin = jcmin_arr[blk];
    int jcmax = i0 >> 5;                 // diagonal chunk (serves both Mt)

    // per-lane embedding constants: d = w*64 + nt*16 + ln15, k = d>>1
    const float c2 = -0.1038102552f;     // -2*log2(10000)/256
    float cr[4];
#pragma unroll
    for (int nt = 0; nt < 4; ++nt) {
        int d = w * 64 + nt * 16 + ln15;
        cr[nt] = exp2f(c2 * (float)((d >> 1) + 1));
    }
    float phase = (ln15 & 1) ? 1.5707963268f : 0.0f;  // cos = sin(x + pi/2)

    // ---- band GEMM: C[m, d] += scores[m, k] * emb[k, d]  (B on the fly)
    f32x4 acc[2][4];
#pragma unroll
    for (int Mt = 0; Mt < 2; ++Mt)
#pragma unroll
        for (int nt = 0; nt < 4; ++nt) acc[Mt][nt] = (f32x4){0.f, 0.f, 0.f, 0.f};

    for (int jc = jcmin; jc < jcmax; ++jc) {      // fully-causal chunks
        int j0 = jc * 32;
        float4 ta4 = *(const float4*)&tb[j0 + kg * 8];
        float4 tb4 = *(const float4*)&tb[j0 + kg * 8 + 4];
        float tj[8] = {ta4.x, ta4.y, ta4.z, ta4.w, tb4.x, tb4.y, tb4.z, tb4.w};

        union { short8 v; unsigned short u[8]; } a0, a1;
#pragma unroll
        for (int e = 0; e < 8; ++e) {
            float d0 = ti0 - tj[e], d1 = ti1 - tj[e];
            a0.u[e] = f2bf(__expf(-0.5f * d0 * d0));
            a1.u[e] = f2bf(__expf(-0.5f * d1 * d1));
        }
#pragma unroll
        for (int nt = 0; nt < 4; ++nt) {
            union { short8 v; unsigned short u[8]; } bf;
#pragma unroll
            for (int e = 0; e < 8; ++e)
                bf.u[e] = f2bf(__sinf(fmaf(tj[e], cr[nt], phase)));
            acc[0][nt] = __builtin_amdgcn_mfma_f32_16x16x32_bf16(a0.v, bf.v, acc[0][nt], 0, 0, 0);
            acc[1][nt] = __builtin_amdgcn_mfma_f32_16x16x32_bf16(a1.v, bf.v, acc[1][nt], 0, 0, 0);
        }
    }
    {   // peeled diagonal chunk jc == jcmax (causal masks for both Mt)
        int j0 = jcmax * 32;
        float4 ta4 = *(const float4*)&tb[j0 + kg * 8];
        float4 tb4 = *(const float4*)&tb[j0 + kg * 8 + 4];
        float tj[8] = {ta4.x, ta4.y, ta4.z, ta4.w, tb4.x, tb4.y, tb4.z, tb4.w};

        union { short8 v; unsigned short u[8]; } a0, a1;
#pragma unroll
        for (int e = 0; e < 8; ++e) {
            int j = j0 + kg * 8 + e;
            float d0 = ti0 - tj[e], d1 = ti1 - tj[e];
            float s0 = __expf(-0.5f * d0 * d0), s1 = __expf(-0.5f * d1 * d1);
            a0.u[e] = (j <= ir0) ? f2bf(s0) : (unsigned short)0;
            a1.u[e] = (j <= ir1) ? f2bf(s1) : (unsigned short)0;
        }
#pragma unroll
        for (int nt = 0; nt < 4; ++nt) {
            union { short8 v; unsigned short u[8]; } bf;
#pragma unroll
            for (int e = 0; e < 8; ++e)
                bf.u[e] = f2bf(__sinf(fmaf(tj[e], cr[nt], phase)));
            acc[0][nt] = __builtin_amdgcn_mfma_f32_16x16x32_bf16(a0.v, bf.v, acc[0][nt], 0, 0, 0);
            acc[1][nt] = __builtin_amdgcn_mfma_f32_16x16x32_bf16(a1.v, bf.v, acc[1][nt], 0, 0, 0);
        }
    }

    // ---- hoist decoder kt=0 weight frags (independent of LN barriers)
    const unsigned short* wbase = w5 + (size_t)(w * 4 * 8) * 512 + lane * 8;
    short8 w0 = *(const short8*)(wbase + (size_t)(0 * 8) * 512);
    short8 w1 = *(const short8*)(wbase + (size_t)(1 * 8) * 512);
    short8 w2 = *(const short8*)(wbase + (size_t)(2 * 8) * 512);
    short8 w3 = *(const short8*)(wbase + (size_t)(3 * 8) * 512);

    // ---- LayerNorm (row r = Mt*16 + kg*4 + reg; col d = w*64 + nt*16 + ln15)
    __shared__ float2 s_ln[4][RPB];
    __shared__ unsigned short H[RPB][264];       // +8 pad
    __shared__ float s_dec[4][RPB];

#pragma unroll
    for (int Mt = 0; Mt < 2; ++Mt)
#pragma unroll
        for (int reg = 0; reg < 4; ++reg) {
            float s = acc[Mt][0][reg] + acc[Mt][1][reg] + acc[Mt][2][reg] + acc[Mt][3][reg];
            float q = acc[Mt][0][reg] * acc[Mt][0][reg] + acc[Mt][1][reg] * acc[Mt][1][reg]
                    + acc[Mt][2][reg] * acc[Mt][2][reg] + acc[Mt][3][reg] * acc[Mt][3][reg];
#pragma unroll
            for (int m = 1; m < 16; m <<= 1) {
                s += __shfl_xor(s, m);
                q += __shfl_xor(q, m);
            }
            if (ln15 == 0) s_ln[w][Mt * 16 + kg * 4 + reg] = make_float2(s, q);
        }
    __syncthreads();

    float g[4], be[4];
#pragma unroll
    for (int nt = 0; nt < 4; ++nt) {
        g[nt]  = gamma[w * 64 + nt * 16 + ln15];
        be[nt] = beta[w * 64 + nt * 16 + ln15];
    }
#pragma unroll
    for (int Mt = 0; Mt < 2; ++Mt)
#pragma unroll
        for (int reg = 0; reg < 4; ++reg) {
            int r = Mt * 16 + kg * 4 + reg;
            float2 p0 = s_ln[0][r], p1 = s_ln[1][r], p2 = s_ln[2][r], p3 = s_ln[3][r];
            float sum = p0.x + p1.x + p2.x + p3.x;
            float sq  = p0.y + p1.y + p2.y + p3.y;
            float mu  = sum * (1.0f / D);
            float var = fmaxf(sq * (1.0f / D) - mu * mu, 0.0f);
            float rstd = rsqrtf(var + 1e-6f);
#pragma unroll
            for (int nt = 0; nt < 4; ++nt) {
                float h = (acc[Mt][nt][reg] - mu) * rstd * g[nt] + be[nt];
                H[r][w * 64 + nt * 16 + ln15] = f2bf(h);
            }
        }
    __syncthreads();

    // ---- decoder GEMM: C2[m, e] = sum_d H[m, d] * W[e, d], kt pipelined;
    //      W-frags reused across both Mt tiles.
    f32x4 acc2[2][4];
#pragma unroll
    for (int Mt = 0; Mt < 2; ++Mt)
#pragma unroll
        for (int et = 0; et < 4; ++et) acc2[Mt][et] = (f32x4){0.f, 0.f, 0.f, 0.f};

#pragma unroll
    for (int kt = 0; kt < 8; ++kt) {
        short8 nw0, nw1, nw2, nw3;
        if (kt < 7) {
            const unsigned short* p = wbase + (size_t)(kt + 1) * 512;
            nw0 = *(const short8*)(p + (size_t)(0 * 8) * 512);
            nw1 = *(const short8*)(p + (size_t)(1 * 8) * 512);
            nw2 = *(const short8*)(p + (size_t)(2 * 8) * 512);
            nw3 = *(const short8*)(p + (size_t)(3 * 8) * 512);
        }
        short8 a0 = *(const short8*)&H[ln15][kt * 32 + kg * 8];
        short8 a1 = *(const short8*)&H[16 + ln15][kt * 32 + kg * 8];
        acc2[0][0] = __builtin_amdgcn_mfma_f32_16x16x32_bf16(a0, w0, acc2[0][0], 0, 0, 0);
        acc2[0][1] = __builtin_amdgcn_mfma_f32_16x16x32_bf16(a0, w1, acc2[0][1], 0, 0, 0);
        acc2[0][2] = __builtin_amdgcn_mfma_f32_16x16x32_bf16(a0, w2, acc2[0][2], 0, 0, 0);
        acc2[0][3] = __builtin_amdgcn_mfma_f32_16x16x32_bf16(a0, w3, acc2[0][3], 0, 0, 0);
        acc2[1][0] = __builtin_amdgcn_mfma_f32_16x16x32_bf16(a1, w0, acc2[1][0], 0, 0, 0);
        acc2[1][1] = __builtin_amdgcn_mfma_f32_16x16x32_bf16(a1, w1, acc2[1][1], 0, 0, 0);
        acc2[1][2] = __builtin_amdgcn_mfma_f32_16x16x32_bf16(a1, w2, acc2[1][2], 0, 0, 0);
        acc2[1][3] = __builtin_amdgcn_mfma_f32_16x16x32_bf16(a1, w3, acc2[1][3], 0, 0, 0);
        w0 = nw0; w1 = nw1; w2 = nw2; w3 = nw3;
    }

    // ---- epilogue: relu -> *w_t -> reduce over e -> softplus
    float wt[4];
#pragma unroll
    for (int et = 0; et < 4; ++et) wt[et] = w_t[w * 64 + et * 16 + ln15];
#pragma unroll
    for (int Mt = 0; Mt < 2; ++Mt)
#pragma unroll
        for (int reg = 0; reg < 4; ++reg) {
            float v = 0.f;
#pragma unroll
            for (int et = 0; et < 4; ++et)
                v = fmaf(fmaxf(acc2[Mt][et][reg], 0.f), wt[et], v);
#pragma unroll
            for (int m = 1; m < 16; m <<= 1) v += __shfl_xor(v, m);
            if (ln15 == 0) s_dec[w][Mt * 16 + kg * 4 + reg] = v;
        }
    __syncthreads();
    if (tid < RPB) {
        float tot = s_dec[0][tid] + s_dec[1][tid] + s_dec[2][tid] + s_dec[3][tid] + b_t[0];
        float o = fmaxf(tot, 0.0f) + log1pf(expf(-fabsf(tot)));   // softplus
        out[(size_t)blk * RPB + tid] = o;
    }
}

// ---------------------------------------------------------------------------
extern "C" void kernel_launch(void* const* d_in, const int* in_sizes, int n_in,
                              void* d_out, int out_size, void* d_ws, size_t ws_size,
                              hipStream_t stream) {
    // inputs: 0 event_type(i32) 1 event_time(f32) 2 arrival_times(f32)
    //         3 W_in 4 w_t 5 b_t 6 ln_gamma 7 ln_beta
    const float* t   = (const float*)d_in[1];
    const float* W   = (const float*)d_in[3];
    const float* wt  = (const float*)d_in[4];
    const float* bt  = (const float*)d_in[5];
    const float* gam = (const float*)d_in[6];
    const float* bet = (const float*)d_in[7];
    float* out = (float*)d_out;

    char* ws = (char*)d_ws;
    unsigned short* w5    = (unsigned short*)ws;                 // 128 KiB
    int*            jcmin = (int*)(ws + (size_t)131072);         // 2 KiB

    prep_kernel<<<dim3(256), dim3(256), 0, stream>>>(t, W, w5, jcmin);
    fused_kernel<<<dim3(NBLK), dim3(256), 0, stream>>>(
        t, w5, jcmin, gam, bet, wt, bt, out);
}